// Round 1
// baseline (362.188 us; speedup 1.0000x reference)
//
#include <hip/hip_runtime.h>
#include <hip/hip_bf16.h>

// GCN decoder: 3x [msg = h@W + b; h = relu(adj @ msg)] then out = (h@Wout + bout)*mask
// B=8, N=2048, latent=64, hidden=128, out=64. All compute in bf16 MFMA (32x32x16), fp32 accum.

typedef __bf16 bf16;
typedef __bf16 bf16x8 __attribute__((ext_vector_type(8)));
typedef float  f32x16 __attribute__((ext_vector_type(16)));
typedef float  f32x4  __attribute__((ext_vector_type(4)));

static __device__ inline f32x16 mfma32(bf16x8 a, bf16x8 b, f32x16 c) {
    return __builtin_amdgcn_mfma_f32_32x32x16_bf16(a, b, c, 0, 0, 0);
}

#define NB    8
#define NN    2048
#define LAT   64
#define HID   128
#define ODIM  64

// ---------------- setup: bf16 conversions + weight transposes ----------------
// latbf[g][k] = bf16(latent[g][k]); WTl[fo][k] = bf16(Wl[k][fo]); WoutT[o][k] = bf16(Wout[k][o])
__global__ __launch_bounds__(256) void setup_k(
    const float* __restrict__ lat,
    const float* __restrict__ W0, const float* __restrict__ W1,
    const float* __restrict__ W2, const float* __restrict__ Wout,
    bf16* __restrict__ latbf, bf16* __restrict__ WT0, bf16* __restrict__ WT1,
    bf16* __restrict__ WT2, bf16* __restrict__ WoutT)
{
    int i = blockIdx.x * 256 + threadIdx.x;
    const int LATSZ = NB * NN * LAT;          // 1048576
    if (i < LATSZ) { latbf[i] = (bf16)lat[i]; return; }
    i -= LATSZ;
    if (i < HID * LAT) {                      // WT0 [128][64]
        int fo = i >> 6, k = i & 63;
        WT0[i] = (bf16)W0[k * HID + fo]; return;
    }
    i -= HID * LAT;
    if (i < HID * HID) {                      // WT1 [128][128]
        int fo = i >> 7, k = i & 127;
        WT1[i] = (bf16)W1[k * HID + fo]; return;
    }
    i -= HID * HID;
    if (i < HID * HID) {                      // WT2 [128][128]
        int fo = i >> 7, k = i & 127;
        WT2[i] = (bf16)W2[k * HID + fo]; return;
    }
    i -= HID * HID;
    if (i < ODIM * HID) {                     // WoutT [64][128]
        int o = i >> 7, k = i & 127;
        WoutT[i] = (bf16)Wout[k * ODIM + o]; return;
    }
}

// ---------------- transform: msgT[b][fo][n] = h[g][:] @ W[:,fo] + bias[fo] ----------------
// GEMM C[fo][node] = WT[fo][k] * h[node][k]. Block: 64 nodes x 128 fo; 4 waves, wave w -> fo tile.
__global__ __launch_bounds__(256) void transform_k(
    const bf16* __restrict__ hin, const bf16* __restrict__ WT,
    const float* __restrict__ bias, bf16* __restrict__ msgT, int din)
{
    int tid = threadIdx.x;
    int l = tid & 63, w = tid >> 6;
    int lm = l & 31, lh = l >> 5;
    int g0 = blockIdx.x * 64;          // global node base (stays within one batch: 2048%64==0)
    int b  = g0 >> 11;
    int nb = g0 & 2047;

    const bf16* Wrow = WT + (size_t)(w * 32 + lm) * din + lh * 8;
    const bf16* h0   = hin + (size_t)(g0 + lm) * din + lh * 8;
    const bf16* h1   = h0 + (size_t)32 * din;

    f32x16 acc0 = {}, acc1 = {};
    for (int k0 = 0; k0 < din; k0 += 16) {
        bf16x8 a  = *(const bf16x8*)(Wrow + k0);
        bf16x8 v0 = *(const bf16x8*)(h0 + k0);
        bf16x8 v1 = *(const bf16x8*)(h1 + k0);
        acc0 = mfma32(a, v0, acc0);
        acc1 = mfma32(a, v1, acc1);
    }

    bf16* outb = msgT + (size_t)b * (HID * NN) + nb;
#pragma unroll
    for (int r = 0; r < 16; ++r) {
        int fo = w * 32 + (r & 3) + 8 * (r >> 2) + 4 * lh;
        float bv = bias[fo];
        outb[(size_t)fo * NN + lm]      = (bf16)(acc0[r] + bv);
        outb[(size_t)fo * NN + 32 + lm] = (bf16)(acc1[r] + bv);
    }
}

// ---------------- aggregate: h[b][n][f] = relu( sum_k adj[b][n][k] * msg[k][f] ) ----------------
// Block: 32 nodes x 128 feats, 4 waves (one 32-f tile each). adj fp32 -> bf16 staged in LDS.
__global__ __launch_bounds__(256) void aggregate_k(
    const float* __restrict__ adj, const bf16* __restrict__ msgT,
    bf16* __restrict__ hout)
{
    __shared__ __align__(16) bf16 As[32 * 72];  // stride 72 (144 B): 4-phase-optimal b128 reads
    int tid = threadIdx.x;
    int l = tid & 63, w = tid >> 6;
    int lm = l & 31, lh = l >> 5;
    int b  = blockIdx.x >> 6;
    int m0 = (blockIdx.x & 63) * 32;

    const float* adjb = adj + (size_t)b * NN * NN + (size_t)m0 * NN;
    const bf16*  msgb = msgT + (size_t)(b * HID + w * 32 + lm) * NN + lh * 8;

    int srow = tid >> 3, scol = (tid & 7) * 8;
    const float* srcb = adjb + (size_t)srow * NN + scol;
    bf16* sdst = &As[srow * 72 + scol];

    f32x16 acc = {};
    for (int k0 = 0; k0 < NN; k0 += 64) {
        f32x4 x0 = *(const f32x4*)(srcb + k0);
        f32x4 x1 = *(const f32x4*)(srcb + k0 + 4);
        bf16x8 v;
        v[0] = (bf16)x0[0]; v[1] = (bf16)x0[1]; v[2] = (bf16)x0[2]; v[3] = (bf16)x0[3];
        v[4] = (bf16)x1[0]; v[5] = (bf16)x1[1]; v[6] = (bf16)x1[2]; v[7] = (bf16)x1[3];
        __syncthreads();                 // previous iter's reads done
        *(bf16x8*)sdst = v;
        __syncthreads();                 // staging visible
#pragma unroll
        for (int s = 0; s < 4; ++s) {
            bf16x8 a  = *(const bf16x8*)&As[lm * 72 + s * 16 + lh * 8];
            bf16x8 bb = *(const bf16x8*)(msgb + k0 + s * 16);
            acc = mfma32(a, bb, acc);
        }
    }

    bf16* outb = hout + ((size_t)b * NN + m0) * HID + w * 32;
#pragma unroll
    for (int r = 0; r < 16; ++r) {
        int row = (r & 3) + 8 * (r >> 2) + 4 * lh;
        float v = acc[r];
        outb[(size_t)row * HID + lm] = (bf16)(v > 0.f ? v : 0.f);
    }
}

// ---------------- output: out[g][o] = (h[g][:] @ Wout[:,o] + bout[o]) * mask[g] ----------------
// GEMM C[node][o] = h[node][k] * WoutT[o][k]. Block: 128 nodes; wave w -> 32 nodes, 2 o-tiles.
__global__ __launch_bounds__(256) void output_k(
    const bf16* __restrict__ h, const bf16* __restrict__ WoutT,
    const float* __restrict__ bout, const float* __restrict__ mask,
    float* __restrict__ out)
{
    int tid = threadIdx.x;
    int l = tid & 63, w = tid >> 6;
    int lm = l & 31, lh = l >> 5;
    int g0 = blockIdx.x * 128 + w * 32;

    const bf16* hrow = h + (size_t)(g0 + lm) * HID + lh * 8;
    const bf16* wr0  = WoutT + (size_t)lm * HID + lh * 8;
    const bf16* wr1  = WoutT + (size_t)(32 + lm) * HID + lh * 8;

    f32x16 acc0 = {}, acc1 = {};
    for (int k0 = 0; k0 < HID; k0 += 16) {
        bf16x8 a  = *(const bf16x8*)(hrow + k0);
        bf16x8 b0 = *(const bf16x8*)(wr0 + k0);
        bf16x8 b1 = *(const bf16x8*)(wr1 + k0);
        acc0 = mfma32(a, b0, acc0);
        acc1 = mfma32(a, b1, acc1);
    }

    float bv0 = bout[lm], bv1 = bout[32 + lm];
#pragma unroll
    for (int r = 0; r < 16; ++r) {
        int node = g0 + (r & 3) + 8 * (r >> 2) + 4 * lh;
        float mk = mask[node];
        out[(size_t)node * ODIM + lm]      = (acc0[r] + bv0) * mk;
        out[(size_t)node * ODIM + 32 + lm] = (acc1[r] + bv1) * mk;
    }
}

extern "C" void kernel_launch(void* const* d_in, const int* in_sizes, int n_in,
                              void* d_out, int out_size, void* d_ws, size_t ws_size,
                              hipStream_t stream)
{
    const float* lat  = (const float*)d_in[0];
    const float* adj  = (const float*)d_in[1];
    const float* mask = (const float*)d_in[2];
    const float* W0   = (const float*)d_in[3];
    const float* b0   = (const float*)d_in[4];
    const float* W1   = (const float*)d_in[5];
    const float* b1   = (const float*)d_in[6];
    const float* W2   = (const float*)d_in[7];
    const float* b2   = (const float*)d_in[8];
    const float* Wout = (const float*)d_in[9];
    const float* bout = (const float*)d_in[10];
    float* out = (float*)d_out;

    char* ws = (char*)d_ws;
    bf16* latbf = (bf16*)(ws + 0);          // 16384*64*2  = 2 MiB
    bf16* h     = (bf16*)(ws + 2097152);    // 16384*128*2 = 4 MiB
    bf16* msgT  = (bf16*)(ws + 6291456);    // 8*128*2048*2 = 4 MiB
    bf16* WT0   = (bf16*)(ws + 10485760);   // 16 KiB
    bf16* WT1   = (bf16*)(ws + 10502144);   // 32 KiB
    bf16* WT2   = (bf16*)(ws + 10534912);   // 32 KiB
    bf16* WoutT = (bf16*)(ws + 10567680);   // 16 KiB

    // total setup elements: 1048576 + 8192 + 16384 + 16384 + 8192 = 1097728 = 4288*256
    setup_k<<<4288, 256, 0, stream>>>(lat, W0, W1, W2, Wout, latbf, WT0, WT1, WT2, WoutT);

    transform_k<<<256, 256, 0, stream>>>(latbf, WT0, b0, msgT, LAT);
    aggregate_k<<<512, 256, 0, stream>>>(adj, msgT, h);

    transform_k<<<256, 256, 0, stream>>>(h, WT1, b1, msgT, HID);
    aggregate_k<<<512, 256, 0, stream>>>(adj, msgT, h);

    transform_k<<<256, 256, 0, stream>>>(h, WT2, b2, msgT, HID);
    aggregate_k<<<512, 256, 0, stream>>>(adj, msgT, h);

    output_k<<<128, 256, 0, stream>>>(h, WoutT, bout, mask, out);
}

// Round 2
// 344.931 us; speedup vs baseline: 1.0500x; 1.0500x over previous
//
#include <hip/hip_runtime.h>
#include <hip/hip_bf16.h>

// GCN decoder: 3x [msg = h@W + b; h = relu(adj @ msg)] then out = (h@Wout + bout)*mask
// B=8, N=2048, latent=64, hidden=128, out=64. All compute in bf16 MFMA (32x32x16), fp32 accum.

typedef __bf16 bf16;
typedef __bf16 bf16x8 __attribute__((ext_vector_type(8)));
typedef float  f32x16 __attribute__((ext_vector_type(16)));
typedef float  f32x4  __attribute__((ext_vector_type(4)));

static __device__ inline f32x16 mfma32(bf16x8 a, bf16x8 b, f32x16 c) {
    return __builtin_amdgcn_mfma_f32_32x32x16_bf16(a, b, c, 0, 0, 0);
}

#define NB    8
#define NN    2048
#define LAT   64
#define HID   128
#define ODIM  64

// ---------------- setup: bf16 conversions + weight transposes ----------------
__global__ __launch_bounds__(256) void setup_k(
    const float* __restrict__ lat,
    const float* __restrict__ W0, const float* __restrict__ W1,
    const float* __restrict__ W2, const float* __restrict__ Wout,
    bf16* __restrict__ latbf, bf16* __restrict__ WT0, bf16* __restrict__ WT1,
    bf16* __restrict__ WT2, bf16* __restrict__ WoutT)
{
    int i = blockIdx.x * 256 + threadIdx.x;
    const int LATSZ = NB * NN * LAT;          // 1048576
    if (i < LATSZ) { latbf[i] = (bf16)lat[i]; return; }
    i -= LATSZ;
    if (i < HID * LAT) {                      // WT0 [128][64]
        int fo = i >> 6, k = i & 63;
        WT0[i] = (bf16)W0[k * HID + fo]; return;
    }
    i -= HID * LAT;
    if (i < HID * HID) {                      // WT1 [128][128]
        int fo = i >> 7, k = i & 127;
        WT1[i] = (bf16)W1[k * HID + fo]; return;
    }
    i -= HID * HID;
    if (i < HID * HID) {                      // WT2 [128][128]
        int fo = i >> 7, k = i & 127;
        WT2[i] = (bf16)W2[k * HID + fo]; return;
    }
    i -= HID * HID;
    if (i < ODIM * HID) {                     // WoutT [64][128]
        int o = i >> 7, k = i & 127;
        WoutT[i] = (bf16)Wout[k * ODIM + o]; return;
    }
}

// ---------------- transform: msgT[b][fo][n] = h[g][:] @ W[:,fo] + bias[fo] ----------------
__global__ __launch_bounds__(256) void transform_k(
    const bf16* __restrict__ hin, const bf16* __restrict__ WT,
    const float* __restrict__ bias, bf16* __restrict__ msgT, int din)
{
    int tid = threadIdx.x;
    int l = tid & 63, w = tid >> 6;
    int lm = l & 31, lh = l >> 5;
    int g0 = blockIdx.x * 64;
    int b  = g0 >> 11;
    int nb = g0 & 2047;

    const bf16* Wrow = WT + (size_t)(w * 32 + lm) * din + lh * 8;
    const bf16* h0   = hin + (size_t)(g0 + lm) * din + lh * 8;
    const bf16* h1   = h0 + (size_t)32 * din;

    f32x16 acc0 = {}, acc1 = {};
    for (int k0 = 0; k0 < din; k0 += 16) {
        bf16x8 a  = *(const bf16x8*)(Wrow + k0);
        bf16x8 v0 = *(const bf16x8*)(h0 + k0);
        bf16x8 v1 = *(const bf16x8*)(h1 + k0);
        acc0 = mfma32(a, v0, acc0);
        acc1 = mfma32(a, v1, acc1);
    }

    bf16* outb = msgT + (size_t)b * (HID * NN) + nb;
#pragma unroll
    for (int r = 0; r < 16; ++r) {
        int fo = w * 32 + (r & 3) + 8 * (r >> 2) + 4 * lh;
        float bv = bias[fo];
        outb[(size_t)fo * NN + lm]      = (bf16)(acc0[r] + bv);
        outb[(size_t)fo * NN + 32 + lm] = (bf16)(acc1[r] + bv);
    }
}

// ---------------- aggregate: h[b][n][f] = relu( sum_k adj[b][n][k] * msg[k][f] ) ----------------
// Block: 32 nodes x 128 feats, 4 waves. A (adj fp32->bf16) AND B (msg bf16) staged via LDS,
// double-buffered, register prefetch, ONE barrier per 64-K tile.
__global__ __launch_bounds__(256) void aggregate_k(
    const float* __restrict__ adj, const bf16* __restrict__ msgT,
    bf16* __restrict__ hout)
{
    __shared__ __align__(16) bf16 As[2][32 * 72];   // stride 72: conflict-free b128
    __shared__ __align__(16) bf16 Bs[2][128 * 72];
    int tid = threadIdx.x;
    int l = tid & 63, w = tid >> 6;
    int lm = l & 31, lh = l >> 5;
    int b  = blockIdx.x >> 6;
    int m0 = (blockIdx.x & 63) * 32;

    const float* adjb = adj + (size_t)b * NN * NN + (size_t)m0 * NN;
    const bf16*  msgb = msgT + (size_t)b * (HID * NN);

    // A staging: thread -> adj row tid>>3, col chunk (tid&7)*8 (32 B fp32, coalesced 128B groups)
    int arow = tid >> 3, acol = (tid & 7) * 8;
    const float* asrc = adjb + (size_t)arow * NN + acol;
    // B staging: thread -> msg feat row tid>>1, 32-elem half (tid&1)*32 (64 B bf16, coalesced)
    int bfeat = tid >> 1, bcol = (tid & 1) * 32;
    const bf16* bsrc = msgb + (size_t)bfeat * NN + bcol;

    f32x4 pa0, pa1;
    bf16x8 pb0, pb1, pb2, pb3;

    // prologue: tile 0
    pa0 = *(const f32x4*)(asrc);
    pa1 = *(const f32x4*)(asrc + 4);
    pb0 = *(const bf16x8*)(bsrc);
    pb1 = *(const bf16x8*)(bsrc + 8);
    pb2 = *(const bf16x8*)(bsrc + 16);
    pb3 = *(const bf16x8*)(bsrc + 24);
    {
        bf16x8 va;
        va[0] = (bf16)pa0[0]; va[1] = (bf16)pa0[1]; va[2] = (bf16)pa0[2]; va[3] = (bf16)pa0[3];
        va[4] = (bf16)pa1[0]; va[5] = (bf16)pa1[1]; va[6] = (bf16)pa1[2]; va[7] = (bf16)pa1[3];
        *(bf16x8*)&As[0][arow * 72 + acol] = va;
        *(bf16x8*)&Bs[0][bfeat * 72 + bcol]      = pb0;
        *(bf16x8*)&Bs[0][bfeat * 72 + bcol + 8]  = pb1;
        *(bf16x8*)&Bs[0][bfeat * 72 + bcol + 16] = pb2;
        *(bf16x8*)&Bs[0][bfeat * 72 + bcol + 24] = pb3;
    }
    __syncthreads();

    f32x16 acc = {};
    for (int kt = 0; kt < 32; ++kt) {
        int cur = kt & 1;
        int k1 = (kt + 1) * 64;
        bool more = (kt + 1 < 32);
        if (more) {   // issue next tile's global loads (in flight during MFMAs)
            pa0 = *(const f32x4*)(asrc + k1);
            pa1 = *(const f32x4*)(asrc + k1 + 4);
            pb0 = *(const bf16x8*)(bsrc + k1);
            pb1 = *(const bf16x8*)(bsrc + k1 + 8);
            pb2 = *(const bf16x8*)(bsrc + k1 + 16);
            pb3 = *(const bf16x8*)(bsrc + k1 + 24);
        }
        const bf16* Ac = &As[cur][lm * 72 + lh * 8];
        const bf16* Bc = &Bs[cur][(w * 32 + lm) * 72 + lh * 8];
#pragma unroll
        for (int s = 0; s < 4; ++s) {
            bf16x8 a  = *(const bf16x8*)(Ac + s * 16);
            bf16x8 bb = *(const bf16x8*)(Bc + s * 16);
            acc = mfma32(a, bb, acc);
        }
        if (more) {   // write next buffer (safe: readers of it passed last barrier)
            int nxt = cur ^ 1;
            bf16x8 va;
            va[0] = (bf16)pa0[0]; va[1] = (bf16)pa0[1]; va[2] = (bf16)pa0[2]; va[3] = (bf16)pa0[3];
            va[4] = (bf16)pa1[0]; va[5] = (bf16)pa1[1]; va[6] = (bf16)pa1[2]; va[7] = (bf16)pa1[3];
            *(bf16x8*)&As[nxt][arow * 72 + acol] = va;
            *(bf16x8*)&Bs[nxt][bfeat * 72 + bcol]      = pb0;
            *(bf16x8*)&Bs[nxt][bfeat * 72 + bcol + 8]  = pb1;
            *(bf16x8*)&Bs[nxt][bfeat * 72 + bcol + 16] = pb2;
            *(bf16x8*)&Bs[nxt][bfeat * 72 + bcol + 24] = pb3;
        }
        __syncthreads();
    }

    bf16* outb = hout + ((size_t)b * NN + m0) * HID + w * 32;
#pragma unroll
    for (int r = 0; r < 16; ++r) {
        int row = (r & 3) + 8 * (r >> 2) + 4 * lh;
        float v = acc[r];
        outb[(size_t)row * HID + lm] = (bf16)(v > 0.f ? v : 0.f);
    }
}

// ---------------- output: out[g][o] = (h[g][:] @ Wout[:,o] + bout[o]) * mask[g] ----------------
__global__ __launch_bounds__(256) void output_k(
    const bf16* __restrict__ h, const bf16* __restrict__ WoutT,
    const float* __restrict__ bout, const float* __restrict__ mask,
    float* __restrict__ out)
{
    int tid = threadIdx.x;
    int l = tid & 63, w = tid >> 6;
    int lm = l & 31, lh = l >> 5;
    int g0 = blockIdx.x * 128 + w * 32;

    const bf16* hrow = h + (size_t)(g0 + lm) * HID + lh * 8;
    const bf16* wr0  = WoutT + (size_t)lm * HID + lh * 8;
    const bf16* wr1  = WoutT + (size_t)(32 + lm) * HID + lh * 8;

    f32x16 acc0 = {}, acc1 = {};
    for (int k0 = 0; k0 < HID; k0 += 16) {
        bf16x8 a  = *(const bf16x8*)(hrow + k0);
        bf16x8 b0 = *(const bf16x8*)(wr0 + k0);
        bf16x8 b1 = *(const bf16x8*)(wr1 + k0);
        acc0 = mfma32(a, b0, acc0);
        acc1 = mfma32(a, b1, acc1);
    }

    float bv0 = bout[lm], bv1 = bout[32 + lm];
#pragma unroll
    for (int r = 0; r < 16; ++r) {
        int node = g0 + (r & 3) + 8 * (r >> 2) + 4 * lh;
        float mk = mask[node];
        out[(size_t)node * ODIM + lm]      = (acc0[r] + bv0) * mk;
        out[(size_t)node * ODIM + 32 + lm] = (acc1[r] + bv1) * mk;
    }
}

extern "C" void kernel_launch(void* const* d_in, const int* in_sizes, int n_in,
                              void* d_out, int out_size, void* d_ws, size_t ws_size,
                              hipStream_t stream)
{
    const float* lat  = (const float*)d_in[0];
    const float* adj  = (const float*)d_in[1];
    const float* mask = (const float*)d_in[2];
    const float* W0   = (const float*)d_in[3];
    const float* b0   = (const float*)d_in[4];
    const float* W1   = (const float*)d_in[5];
    const float* b1   = (const float*)d_in[6];
    const float* W2   = (const float*)d_in[7];
    const float* b2   = (const float*)d_in[8];
    const float* Wout = (const float*)d_in[9];
    const float* bout = (const float*)d_in[10];
    float* out = (float*)d_out;

    char* ws = (char*)d_ws;
    bf16* latbf = (bf16*)(ws + 0);          // 2 MiB
    bf16* h     = (bf16*)(ws + 2097152);    // 4 MiB
    bf16* msgT  = (bf16*)(ws + 6291456);    // 4 MiB
    bf16* WT0   = (bf16*)(ws + 10485760);
    bf16* WT1   = (bf16*)(ws + 10502144);
    bf16* WT2   = (bf16*)(ws + 10534912);
    bf16* WoutT = (bf16*)(ws + 10567680);

    setup_k<<<4288, 256, 0, stream>>>(lat, W0, W1, W2, Wout, latbf, WT0, WT1, WT2, WoutT);

    transform_k<<<256, 256, 0, stream>>>(latbf, WT0, b0, msgT, LAT);
    aggregate_k<<<512, 256, 0, stream>>>(adj, msgT, h);

    transform_k<<<256, 256, 0, stream>>>(h, WT1, b1, msgT, HID);
    aggregate_k<<<512, 256, 0, stream>>>(adj, msgT, h);

    transform_k<<<256, 256, 0, stream>>>(h, WT2, b2, msgT, HID);
    aggregate_k<<<512, 256, 0, stream>>>(adj, msgT, h);

    output_k<<<128, 256, 0, stream>>>(h, WoutT, bout, mask, out);
}

// Round 3
// 331.814 us; speedup vs baseline: 1.0915x; 1.0395x over previous
//
#include <hip/hip_runtime.h>
#include <hip/hip_bf16.h>

// GCN decoder, fused: prep(WT) ; T0: msg0 = lat@W0+b0 ;
// 3x fused aggregate: h = relu(adj@msg); epilogue GEMM (next transform or output proj).
// All MFMA 32x32x16 bf16, fp32 accum. 5 dispatches total.

typedef __bf16 bf16;
typedef __bf16 bf16x4 __attribute__((ext_vector_type(4)));
typedef __bf16 bf16x8 __attribute__((ext_vector_type(8)));
typedef float  f32x16 __attribute__((ext_vector_type(16)));
typedef float  f32x4  __attribute__((ext_vector_type(4)));

static __device__ inline f32x16 mfma32(bf16x8 a, bf16x8 b, f32x16 c) {
    return __builtin_amdgcn_mfma_f32_32x32x16_bf16(a, b, c, 0, 0, 0);
}

#define NB   8
#define NN   2048
#define LAT  64
#define HID  128
#define ODIM 64

// ---------------- prep: weight transposes to bf16 [fo][k] ----------------
__global__ __launch_bounds__(256) void prep_k(
    const float* __restrict__ W0, const float* __restrict__ W1,
    const float* __restrict__ W2, const float* __restrict__ Wout,
    bf16* __restrict__ WT0, bf16* __restrict__ WT1,
    bf16* __restrict__ WT2, bf16* __restrict__ WoutT)
{
    int i = blockIdx.x * 256 + threadIdx.x;
    if (i < HID * LAT) {                      // WT0 [128][64]
        int fo = i >> 6, k = i & 63;
        WT0[i] = (bf16)W0[k * HID + fo]; return;
    }
    i -= HID * LAT;
    if (i < HID * HID) {                      // WT1 [128][128]
        int fo = i >> 7, k = i & 127;
        WT1[i] = (bf16)W1[k * HID + fo]; return;
    }
    i -= HID * HID;
    if (i < HID * HID) {                      // WT2 [128][128]
        int fo = i >> 7, k = i & 127;
        WT2[i] = (bf16)W2[k * HID + fo]; return;
    }
    i -= HID * HID;
    if (i < ODIM * HID) {                     // WoutT [64][128]
        int o = i >> 7, k = i & 127;
        WoutT[i] = (bf16)Wout[k * ODIM + o]; return;
    }
}

// ---------------- transform0: msgT[b][fo][n] = lat[g][:] @ W0[:,fo] + b0 ----------------
// Reads fp32 latent directly (cvt in-register); C[fo][node] via A=WT0 rows, B=node cols.
__global__ __launch_bounds__(256) void transform0_k(
    const float* __restrict__ lat, const bf16* __restrict__ WT0,
    const float* __restrict__ b0, bf16* __restrict__ msgT)
{
    int tid = threadIdx.x;
    int l = tid & 63, w = tid >> 6;
    int lm = l & 31, lh = l >> 5;
    int g0 = blockIdx.x * 64;
    int b  = g0 >> 11, nb = g0 & 2047;

    const bf16*  Wrow = WT0 + (size_t)(w * 32 + lm) * LAT + lh * 8;
    const float* r0   = lat + (size_t)(g0 + lm) * LAT + lh * 8;
    const float* r1   = r0 + (size_t)32 * LAT;

    f32x16 acc0 = {}, acc1 = {};
    for (int k0 = 0; k0 < LAT; k0 += 16) {
        bf16x8 a  = *(const bf16x8*)(Wrow + k0);
        f32x4 x0 = *(const f32x4*)(r0 + k0), x1 = *(const f32x4*)(r0 + k0 + 4);
        f32x4 y0 = *(const f32x4*)(r1 + k0), y1 = *(const f32x4*)(r1 + k0 + 4);
        bf16x8 v0, v1;
        v0[0]=(bf16)x0[0]; v0[1]=(bf16)x0[1]; v0[2]=(bf16)x0[2]; v0[3]=(bf16)x0[3];
        v0[4]=(bf16)x1[0]; v0[5]=(bf16)x1[1]; v0[6]=(bf16)x1[2]; v0[7]=(bf16)x1[3];
        v1[0]=(bf16)y0[0]; v1[1]=(bf16)y0[1]; v1[2]=(bf16)y0[2]; v1[3]=(bf16)y0[3];
        v1[4]=(bf16)y1[0]; v1[5]=(bf16)y1[1]; v1[6]=(bf16)y1[2]; v1[7]=(bf16)y1[3];
        acc0 = mfma32(a, v0, acc0);
        acc1 = mfma32(a, v1, acc1);
    }

    bf16* outb = msgT + (size_t)b * (HID * NN) + nb;
#pragma unroll
    for (int r = 0; r < 16; ++r) {
        int fo = w * 32 + (r & 3) + 8 * (r >> 2) + 4 * lh;
        float bv = b0[fo];
        outb[(size_t)fo * NN + lm]      = (bf16)(acc0[r] + bv);
        outb[(size_t)fo * NN + 32 + lm] = (bf16)(acc1[r] + bv);
    }
}

// ---------------- fused aggregate ----------------
// h(32 nodes x 128 f) = relu(adj_block @ msgT); then
//   MODE 0: msg_out[fo][node] = WTn @ h^T + biasn   (next layer's transform)
//   MODE 1: out[node][o] = (h @ WoutT^T + bout) * mask
// Staging: A-instr = 4 full 256B adj row-chunks (8 lines); B-instr = 8 full 128B msg
// row-chunks (8 lines). Double-buffered LDS, 1 barrier/K-tile. Stride 72: conflict-free.
template<int MODE>
__global__ __launch_bounds__(256) void agg_fused_k(
    const float* __restrict__ adj, const bf16* __restrict__ msgT,
    const bf16* __restrict__ WTn, const float* __restrict__ biasn,
    bf16* __restrict__ msg_out, const float* __restrict__ mask,
    float* __restrict__ out)
{
    __shared__ __align__(16) bf16 As[2][32 * 72];
    __shared__ __align__(16) bf16 Bs[2][128 * 72];
    __shared__ __align__(16) bf16 Hs[32 * 136];
    int tid = threadIdx.x;
    int l = tid & 63, w = tid >> 6;
    int lm = l & 31, lh = l >> 5;
    int b  = blockIdx.x >> 6;
    int m0 = (blockIdx.x & 63) * 32;

    const float* adjb = adj + (size_t)b * NN * NN + (size_t)m0 * NN;
    const bf16*  msgb = msgT + (size_t)b * (HID * NN);

    // A: thread -> rows {ar, ar+16}, 16B col chunk; 16 lanes cover a full 256B row chunk
    int ar = tid >> 4, ac = (tid & 15) * 4;
    const float* asrc = adjb + (size_t)ar * NN + ac;
    // B: thread -> rows {br, br+32, br+64, br+96}, 16B col chunk; 8 lanes cover 128B row chunk
    int br = tid >> 3, bc = (tid & 7) * 8;
    const bf16* bsrc = msgb + (size_t)br * NN + bc;

    f32x4 pa0, pa1;
    bf16x8 pb0, pb1, pb2, pb3;

    pa0 = *(const f32x4*)(asrc);
    pa1 = *(const f32x4*)(asrc + (size_t)16 * NN);
    pb0 = *(const bf16x8*)(bsrc);
    pb1 = *(const bf16x8*)(bsrc + (size_t)32 * NN);
    pb2 = *(const bf16x8*)(bsrc + (size_t)64 * NN);
    pb3 = *(const bf16x8*)(bsrc + (size_t)96 * NN);
    {
        bf16x4 va0, va1;
        va0[0]=(bf16)pa0[0]; va0[1]=(bf16)pa0[1]; va0[2]=(bf16)pa0[2]; va0[3]=(bf16)pa0[3];
        va1[0]=(bf16)pa1[0]; va1[1]=(bf16)pa1[1]; va1[2]=(bf16)pa1[2]; va1[3]=(bf16)pa1[3];
        *(bf16x4*)&As[0][ar * 72 + ac]        = va0;
        *(bf16x4*)&As[0][(ar + 16) * 72 + ac] = va1;
        *(bf16x8*)&Bs[0][br * 72 + bc]        = pb0;
        *(bf16x8*)&Bs[0][(br + 32) * 72 + bc] = pb1;
        *(bf16x8*)&Bs[0][(br + 64) * 72 + bc] = pb2;
        *(bf16x8*)&Bs[0][(br + 96) * 72 + bc] = pb3;
    }
    __syncthreads();

    f32x16 acc = {};
    for (int kt = 0; kt < 32; ++kt) {
        int cur = kt & 1;
        bool more = kt < 31;
        int k1 = (kt + 1) * 64;
        if (more) {
            pa0 = *(const f32x4*)(asrc + k1);
            pa1 = *(const f32x4*)(asrc + (size_t)16 * NN + k1);
            pb0 = *(const bf16x8*)(bsrc + k1);
            pb1 = *(const bf16x8*)(bsrc + (size_t)32 * NN + k1);
            pb2 = *(const bf16x8*)(bsrc + (size_t)64 * NN + k1);
            pb3 = *(const bf16x8*)(bsrc + (size_t)96 * NN + k1);
        }
        const bf16* Ac = &As[cur][lm * 72 + lh * 8];
        const bf16* Bc = &Bs[cur][(w * 32 + lm) * 72 + lh * 8];
#pragma unroll
        for (int s = 0; s < 4; ++s)
            acc = mfma32(*(const bf16x8*)(Ac + s * 16), *(const bf16x8*)(Bc + s * 16), acc);
        if (more) {
            int nxt = cur ^ 1;
            bf16x4 va0, va1;
            va0[0]=(bf16)pa0[0]; va0[1]=(bf16)pa0[1]; va0[2]=(bf16)pa0[2]; va0[3]=(bf16)pa0[3];
            va1[0]=(bf16)pa1[0]; va1[1]=(bf16)pa1[1]; va1[2]=(bf16)pa1[2]; va1[3]=(bf16)pa1[3];
            *(bf16x4*)&As[nxt][ar * 72 + ac]        = va0;
            *(bf16x4*)&As[nxt][(ar + 16) * 72 + ac] = va1;
            *(bf16x8*)&Bs[nxt][br * 72 + bc]        = pb0;
            *(bf16x8*)&Bs[nxt][(br + 32) * 72 + bc] = pb1;
            *(bf16x8*)&Bs[nxt][(br + 64) * 72 + bc] = pb2;
            *(bf16x8*)&Bs[nxt][(br + 96) * 72 + bc] = pb3;
        }
        __syncthreads();
    }

    // relu(h) tile -> LDS [node][feat] (A/B-frag friendly layout for the epilogue GEMM)
#pragma unroll
    for (int r = 0; r < 16; ++r) {
        int row = (r & 3) + 8 * (r >> 2) + 4 * lh;
        float v = acc[r];
        Hs[row * 136 + w * 32 + lm] = (bf16)(v > 0.f ? v : 0.f);
    }
    __syncthreads();

    if (MODE == 0) {
        // msg_out[fo][m0+node] = sum_f WTn[fo][f] * h[node][f] + biasn[fo]
        const bf16* Arow = WTn + (size_t)(w * 32 + lm) * HID + lh * 8;  // L1-hot, 32 KB
        const bf16* Brow = &Hs[lm * 136 + lh * 8];                      // node lm
        f32x16 acc2 = {};
#pragma unroll
        for (int s = 0; s < 8; ++s)
            acc2 = mfma32(*(const bf16x8*)(Arow + s * 16), *(const bf16x8*)(Brow + s * 16), acc2);
        bf16* outb = msg_out + (size_t)b * (HID * NN) + m0;
#pragma unroll
        for (int r = 0; r < 16; ++r) {
            int fo = w * 32 + (r & 3) + 8 * (r >> 2) + 4 * lh;
            outb[(size_t)fo * NN + lm] = (bf16)(acc2[r] + biasn[fo]);
        }
    } else {
        // out[g][o] = (sum_f h[node][f] * WoutT[o][f] + bout[o]) * mask[g]
        if (w < 2) {
            int ob = w * 32;
            const bf16* Arow = &Hs[lm * 136 + lh * 8];                  // node lm rows
            const bf16* Brow = WTn + (size_t)(ob + lm) * HID + lh * 8;  // WoutT rows (o)
            f32x16 acc2 = {};
#pragma unroll
            for (int s = 0; s < 8; ++s)
                acc2 = mfma32(*(const bf16x8*)(Arow + s * 16), *(const bf16x8*)(Brow + s * 16), acc2);
            float bv = biasn[ob + lm];
#pragma unroll
            for (int r = 0; r < 16; ++r) {
                int node = (r & 3) + 8 * (r >> 2) + 4 * lh;
                int g = b * NN + m0 + node;
                out[(size_t)g * ODIM + ob + lm] = (acc2[r] + bv) * mask[g];
            }
        }
    }
}

extern "C" void kernel_launch(void* const* d_in, const int* in_sizes, int n_in,
                              void* d_out, int out_size, void* d_ws, size_t ws_size,
                              hipStream_t stream)
{
    const float* lat  = (const float*)d_in[0];
    const float* adj  = (const float*)d_in[1];
    const float* mask = (const float*)d_in[2];
    const float* W0   = (const float*)d_in[3];
    const float* b0   = (const float*)d_in[4];
    const float* W1   = (const float*)d_in[5];
    const float* b1   = (const float*)d_in[6];
    const float* W2   = (const float*)d_in[7];
    const float* b2   = (const float*)d_in[8];
    const float* Wout = (const float*)d_in[9];
    const float* bout = (const float*)d_in[10];
    float* out = (float*)d_out;

    char* ws = (char*)d_ws;
    bf16* msgA  = (bf16*)(ws + 0);          // 8*128*2048*2 = 4 MiB
    bf16* msgB  = (bf16*)(ws + 4194304);    // 4 MiB
    bf16* WT0   = (bf16*)(ws + 8388608);    // 16 KiB
    bf16* WT1   = (bf16*)(ws + 8404992);    // 32 KiB
    bf16* WT2   = (bf16*)(ws + 8437760);    // 32 KiB
    bf16* WoutT = (bf16*)(ws + 8470528);    // 16 KiB

    // weights: 8192+16384+16384+8192 = 49152 elems = 192*256
    prep_k<<<192, 256, 0, stream>>>(W0, W1, W2, Wout, WT0, WT1, WT2, WoutT);

    transform0_k<<<256, 256, 0, stream>>>(lat, WT0, b0, msgA);
    agg_fused_k<0><<<512, 256, 0, stream>>>(adj, msgA, WT1, b1, msgB, nullptr, nullptr);
    agg_fused_k<0><<<512, 256, 0, stream>>>(adj, msgB, WT2, b2, msgA, nullptr, nullptr);
    agg_fused_k<1><<<512, 256, 0, stream>>>(adj, msgA, WoutT, bout, nullptr, mask, out);
}

// Round 4
// 284.448 us; speedup vs baseline: 1.2733x; 1.1665x over previous
//
#include <hip/hip_runtime.h>
#include <hip/hip_bf16.h>

// GCN decoder, 4 dispatches:
//  1) prep_t0_k: blocks 0-255 compute msg0 = lat@W0+b0 (W0 transposed via LDS);
//                blocks 256+ transpose W1/W2/Wout to bf16 [fo][k].
//  2-4) agg_k<MODE,ADJW>: h = relu(adj@msg) + fused epilogue GEMM.
//       ADJW=0: read adj fp32, write back bf16 copy. ADJW=1: read bf16 adj.
//       MODE=0: epilogue = next transform (msg_out). MODE=1: output proj * mask.
// XCD swizzle: batch = blockIdx&7 -> each XCD keeps its batch's msg panel L2-hot.
// K-loop: double LDS buffer + depth-2 register prefetch, 1 barrier/tile.

typedef __bf16 bf16;
typedef __bf16 bf16x4 __attribute__((ext_vector_type(4)));
typedef __bf16 bf16x8 __attribute__((ext_vector_type(8)));
typedef float  f32x16 __attribute__((ext_vector_type(16)));
typedef float  f32x4  __attribute__((ext_vector_type(4)));

static __device__ inline f32x16 mfma32(bf16x8 a, bf16x8 b, f32x16 c) {
    return __builtin_amdgcn_mfma_f32_32x32x16_bf16(a, b, c, 0, 0, 0);
}

#define NB   8
#define NN   2048
#define LAT  64
#define HID  128
#define ODIM 64

// ---------------- dispatch 1: transform0 (blocks 0-255) + weight prep (blocks 256+) ----
__global__ __launch_bounds__(256) void prep_t0_k(
    const float* __restrict__ lat, const float* __restrict__ W0,
    const float* __restrict__ b0,
    const float* __restrict__ W1, const float* __restrict__ W2,
    const float* __restrict__ Wout,
    bf16* __restrict__ msgT, bf16* __restrict__ WT1,
    bf16* __restrict__ WT2, bf16* __restrict__ WoutT)
{
    __shared__ __align__(16) bf16 WTs[HID * 72];   // W0^T [fo][k], stride 72
    int tid = threadIdx.x;
    int blk = blockIdx.x;

    if (blk >= 256) {           // weight transposes (tiny)
        int i = (blk - 256) * 256 + tid;
        if (i < HID * HID) { int fo = i >> 7, k = i & 127; WT1[i] = (bf16)W1[k * HID + fo]; return; }
        i -= HID * HID;
        if (i < HID * HID) { int fo = i >> 7, k = i & 127; WT2[i] = (bf16)W2[k * HID + fo]; return; }
        i -= HID * HID;
        if (i < ODIM * HID) { int o = i >> 7, k = i & 127; WoutT[i] = (bf16)Wout[k * ODIM + o]; return; }
        return;
    }

    // stage W0^T into LDS (W0 is [64][128] row-major, coalesced fp32 reads)
    for (int i = tid; i < LAT * HID; i += 256) {
        int k = i >> 7, fo = i & 127;
        WTs[fo * 72 + k] = (bf16)W0[i];
    }
    __syncthreads();

    int l = tid & 63, w = tid >> 6;
    int lm = l & 31, lh = l >> 5;
    int g0 = blk * 64;
    int b  = g0 >> 11, nb = g0 & 2047;

    const bf16*  Wrow = &WTs[(w * 32 + lm) * 72 + lh * 8];
    const float* r0   = lat + (size_t)(g0 + lm) * LAT + lh * 8;
    const float* r1   = r0 + (size_t)32 * LAT;

    f32x16 acc0 = {}, acc1 = {};
#pragma unroll
    for (int k0 = 0; k0 < LAT; k0 += 16) {
        bf16x8 a = *(const bf16x8*)(Wrow + k0);
        f32x4 x0 = *(const f32x4*)(r0 + k0), x1 = *(const f32x4*)(r0 + k0 + 4);
        f32x4 y0 = *(const f32x4*)(r1 + k0), y1 = *(const f32x4*)(r1 + k0 + 4);
        bf16x8 v0, v1;
        v0[0]=(bf16)x0[0]; v0[1]=(bf16)x0[1]; v0[2]=(bf16)x0[2]; v0[3]=(bf16)x0[3];
        v0[4]=(bf16)x1[0]; v0[5]=(bf16)x1[1]; v0[6]=(bf16)x1[2]; v0[7]=(bf16)x1[3];
        v1[0]=(bf16)y0[0]; v1[1]=(bf16)y0[1]; v1[2]=(bf16)y0[2]; v1[3]=(bf16)y0[3];
        v1[4]=(bf16)y1[0]; v1[5]=(bf16)y1[1]; v1[6]=(bf16)y1[2]; v1[7]=(bf16)y1[3];
        acc0 = mfma32(a, v0, acc0);
        acc1 = mfma32(a, v1, acc1);
    }

    bf16* outb = msgT + (size_t)b * (HID * NN) + nb;
#pragma unroll
    for (int r = 0; r < 16; ++r) {
        int fo = w * 32 + (r & 3) + 8 * (r >> 2) + 4 * lh;
        float bv = b0[fo];
        outb[(size_t)fo * NN + lm]      = (bf16)(acc0[r] + bv);
        outb[(size_t)fo * NN + 32 + lm] = (bf16)(acc1[r] + bv);
    }
}

// ---------------- dispatches 2-4: fused aggregate ----------------
template<int MODE, int ADJW>
__global__ __launch_bounds__(256) void agg_k(
    const float* __restrict__ adjf, const bf16* __restrict__ adjbi,
    bf16* __restrict__ adjbo,
    const bf16* __restrict__ msgT, const bf16* __restrict__ WTn,
    const float* __restrict__ biasn, bf16* __restrict__ msg_out,
    const float* __restrict__ mask, float* __restrict__ out)
{
    __shared__ __align__(16) bf16 As[2][32 * 72];
    __shared__ __align__(16) bf16 Bs[2][128 * 72];
    __shared__ __align__(16) bf16 Hs[32 * 136];
    int tid = threadIdx.x;
    int l = tid & 63, w = tid >> 6;
    int lm = l & 31, lh = l >> 5;
    int b  = blockIdx.x & 7;            // XCD swizzle: batch b -> XCD b
    int m0 = (blockIdx.x >> 3) * 32;

    const bf16* msgb = msgT + (size_t)b * (HID * NN);
    int br = tid >> 3, bc = (tid & 7) * 8;
    const bf16* bsrc = msgb + (size_t)br * NN + bc;

    // A staging (fp32 variant): rows {ar, ar+16}, 16B chunks; 16 lanes = full 256B row chunk
    int ar = tid >> 4, ac = (tid & 15) * 4;
    const float* asrc = (ADJW == 0) ? adjf + (size_t)b * NN * NN + (size_t)(m0 + ar) * NN + ac : nullptr;
    bf16* adst = (ADJW == 0) ? adjbo + (size_t)b * NN * NN + (size_t)(m0 + ar) * NN + ac : nullptr;
    // A staging (bf16 variant): row ar8, 16B chunk; 8 lanes = full 128B row chunk
    int ar8 = tid >> 3, ac8 = (tid & 7) * 8;
    const bf16* asrcb = (ADJW == 1) ? adjbi + (size_t)b * NN * NN + (size_t)(m0 + ar8) * NN + ac8 : nullptr;

    f32x4  fa0[2], fa1[2];
    bf16x8 ba[2];
    bf16x8 pb[2][4];

    auto loadTile = [&](int set, int k) {
        if (ADJW == 0) {
            fa0[set] = *(const f32x4*)(asrc + k);
            fa1[set] = *(const f32x4*)(asrc + (size_t)16 * NN + k);
        } else {
            ba[set] = *(const bf16x8*)(asrcb + k);
        }
        pb[set][0] = *(const bf16x8*)(bsrc + k);
        pb[set][1] = *(const bf16x8*)(bsrc + (size_t)32 * NN + k);
        pb[set][2] = *(const bf16x8*)(bsrc + (size_t)64 * NN + k);
        pb[set][3] = *(const bf16x8*)(bsrc + (size_t)96 * NN + k);
    };
    auto storeTile = [&](int set, int buf, int k) {
        if (ADJW == 0) {
            bf16x4 v0, v1;
            v0[0]=(bf16)fa0[set][0]; v0[1]=(bf16)fa0[set][1]; v0[2]=(bf16)fa0[set][2]; v0[3]=(bf16)fa0[set][3];
            v1[0]=(bf16)fa1[set][0]; v1[1]=(bf16)fa1[set][1]; v1[2]=(bf16)fa1[set][2]; v1[3]=(bf16)fa1[set][3];
            *(bf16x4*)&As[buf][ar * 72 + ac]        = v0;
            *(bf16x4*)&As[buf][(ar + 16) * 72 + ac] = v1;
            *(bf16x4*)(adst + k)                    = v0;   // bf16 adj writeback
            *(bf16x4*)(adst + (size_t)16 * NN + k)  = v1;
        } else {
            *(bf16x8*)&As[buf][ar8 * 72 + ac8] = ba[set];
        }
        *(bf16x8*)&Bs[buf][br * 72 + bc]        = pb[set][0];
        *(bf16x8*)&Bs[buf][(br + 32) * 72 + bc] = pb[set][1];
        *(bf16x8*)&Bs[buf][(br + 64) * 72 + bc] = pb[set][2];
        *(bf16x8*)&Bs[buf][(br + 96) * 72 + bc] = pb[set][3];
    };

    f32x16 acc = {};
    auto mfmaTile = [&](int buf) {
        const bf16* Ac = &As[buf][lm * 72 + lh * 8];
        const bf16* Bc = &Bs[buf][(w * 32 + lm) * 72 + lh * 8];
#pragma unroll
        for (int s = 0; s < 4; ++s)
            acc = mfma32(*(const bf16x8*)(Ac + s * 16), *(const bf16x8*)(Bc + s * 16), acc);
    };

    // prologue: tiles 0,1 in flight; commit tile 0
    loadTile(0, 0);
    loadTile(1, 64);
    storeTile(0, 0, 0);
    __syncthreads();

#pragma unroll 1
    for (int kt = 0; kt < 32; kt += 2) {
        if (kt + 2 < 32) loadTile(0, (kt + 2) * 64);   // tile kt+2 -> set0
        mfmaTile(0);                                    // tile kt
        storeTile(1, 1, (kt + 1) * 64);                 // tile kt+1 (loaded 1 iter ago)
        __syncthreads();
        if (kt + 3 < 32) loadTile(1, (kt + 3) * 64);   // tile kt+3 -> set1
        mfmaTile(1);                                    // tile kt+1
        if (kt + 2 < 32) storeTile(0, 0, (kt + 2) * 64);
        __syncthreads();
    }

    // relu(h) -> LDS [node][feat]
#pragma unroll
    for (int r = 0; r < 16; ++r) {
        int row = (r & 3) + 8 * (r >> 2) + 4 * lh;
        float v = acc[r];
        Hs[row * 136 + w * 32 + lm] = (bf16)(v > 0.f ? v : 0.f);
    }
    __syncthreads();

    if (MODE == 0) {
        // msg_out[fo][m0+node] = WTn[fo][:] . h[node][:] + biasn[fo]
        const bf16* Arow = WTn + (size_t)(w * 32 + lm) * HID + lh * 8;
        const bf16* Brow = &Hs[lm * 136 + lh * 8];
        f32x16 acc2 = {};
#pragma unroll
        for (int s = 0; s < 8; ++s)
            acc2 = mfma32(*(const bf16x8*)(Arow + s * 16), *(const bf16x8*)(Brow + s * 16), acc2);
        bf16* outb = msg_out + (size_t)b * (HID * NN) + m0;
#pragma unroll
        for (int r = 0; r < 16; ++r) {
            int fo = w * 32 + (r & 3) + 8 * (r >> 2) + 4 * lh;
            outb[(size_t)fo * NN + lm] = (bf16)(acc2[r] + biasn[fo]);
        }
    } else {
        if (w < 2) {
            int ob = w * 32;
            const bf16* Arow = &Hs[lm * 136 + lh * 8];
            const bf16* Brow = WTn + (size_t)(ob + lm) * HID + lh * 8;
            f32x16 acc2 = {};
#pragma unroll
            for (int s = 0; s < 8; ++s)
                acc2 = mfma32(*(const bf16x8*)(Arow + s * 16), *(const bf16x8*)(Brow + s * 16), acc2);
            float bv = biasn[ob + lm];
#pragma unroll
            for (int r = 0; r < 16; ++r) {
                int node = (r & 3) + 8 * (r >> 2) + 4 * lh;
                int g = b * NN + m0 + node;
                out[(size_t)g * ODIM + ob + lm] = (acc2[r] + bv) * mask[g];
            }
        }
    }
}

extern "C" void kernel_launch(void* const* d_in, const int* in_sizes, int n_in,
                              void* d_out, int out_size, void* d_ws, size_t ws_size,
                              hipStream_t stream)
{
    const float* lat  = (const float*)d_in[0];
    const float* adj  = (const float*)d_in[1];
    const float* mask = (const float*)d_in[2];
    const float* W0   = (const float*)d_in[3];
    const float* b0   = (const float*)d_in[4];
    const float* W1   = (const float*)d_in[5];
    const float* b1   = (const float*)d_in[6];
    const float* W2   = (const float*)d_in[7];
    const float* b2   = (const float*)d_in[8];
    const float* Wout = (const float*)d_in[9];
    const float* bout = (const float*)d_in[10];
    float* out = (float*)d_out;

    char* ws = (char*)d_ws;
    bf16* msgA  = (bf16*)(ws + 0);            // 4 MiB
    bf16* msgB  = (bf16*)(ws + 4194304);      // 4 MiB
    bf16* adjbf = (bf16*)(ws + 8388608);      // 8*2048*2048*2 = 64 MiB
    bf16* WT1   = (bf16*)(ws + 75497472);     // 32 KiB
    bf16* WT2   = (bf16*)(ws + 75530240);     // 32 KiB
    bf16* WoutT = (bf16*)(ws + 75563008);     // 16 KiB

    // blocks 0-255: transform0; blocks 256-415: weight transposes (40960 elems)
    prep_t0_k<<<416, 256, 0, stream>>>(lat, W0, b0, W1, W2, Wout, msgA, WT1, WT2, WoutT);

    agg_k<0, 0><<<512, 256, 0, stream>>>(adj, nullptr, adjbf, msgA, WT1, b1, msgB, nullptr, nullptr);
    agg_k<0, 1><<<512, 256, 0, stream>>>(nullptr, adjbf, nullptr, msgB, WT2, b2, msgA, nullptr, nullptr);
    agg_k<1, 1><<<512, 256, 0, stream>>>(nullptr, adjbf, nullptr, msgA, WoutT, bout, nullptr, mask, out);
}